// Round 6
// baseline (36.252 us; speedup 1.0000x reference)
//
#include <hip/hip_runtime.h>
#include <math.h>

// B=4096, O=8, E=64, I=4, V=3, P=perm(8,3)=336
// unary_feats  (B,8,64)   f32
// binary_feats (B,8,8,64) f32
// rule_unary   (4,3,64)   f32  = [12][64]
// rule_binary  (4,3,3,64) f32  = [36][64]
// out          (B,4)      f32  (col0=sel0+sel1, col1=sel2+sel3, col2=col3=0)
//
// v6: single dispatch (prep folded in; rules are L1-hot so per-block f32->bf16
// cvt is ~free). Binary match via v_mfma_f32_16x16x32_bf16; bm stored
// transposed [pos][col] with column-permuted rule slots + unary fused:
//   slots 0..2 : r1(01) r2(02) r5(12)     read at row x*8+y
//   slots 4..6 : r3(10) r6(20) r7(21)     read at row y*8+x
//   slots 8..11: r4(11) r8(22) um1 um2    read at row y*8+y (diag)
//   slots 12,13: r0(00) um0               read at row x*8+x (diag)
// Phases 2+3 are WAVE-LOCAL in rule-set i=w -> only 2 block barriers total.
// OOB tile rows handled by address clamping (dup loads, cols never stored).

typedef __attribute__((ext_vector_type(8))) __bf16 bf16x8;
typedef __attribute__((ext_vector_type(4))) float  f32x4;

#define BMT_STRIDE 68   // floats/row; even slot distribution for phase-2 b128
#define QROW 12         // q-table row stride (floats): <=2-way banks, 16B-aligned

__device__ inline bf16x8 load_bf16x8(const float* __restrict__ p) {
    const float4 v0 = *(const float4*)p;
    const float4 v1 = *(const float4*)(p + 4);
    bf16x8 r;
    r[0] = (__bf16)v0.x; r[1] = (__bf16)v0.y; r[2] = (__bf16)v0.z; r[3] = (__bf16)v0.w;
    r[4] = (__bf16)v1.x; r[5] = (__bf16)v1.y; r[6] = (__bf16)v1.z; r[7] = (__bf16)v1.w;
    return r;
}

__global__ __launch_bounds__(256) void rule_learner_kernel(
    const float* __restrict__ uf,    // (B,8,64)
    const float* __restrict__ bfe,   // (B,8,8,64)
    const float* __restrict__ ru,    // [12][64]
    const float* __restrict__ rb,    // [36][64]
    float* __restrict__ out)         // (B,4)
{
    const int b     = blockIdx.x;
    const int tid   = threadIdx.x;
    const int lane  = tid & 63;
    const int w     = tid >> 6;      // wave id = position strip = rule set
    const int row16 = lane & 15;
    const int kg    = lane >> 4;
    const int kb    = kg * 8;

    __shared__ float bm_t[64 * BMT_STRIDE];  // 17408 B
    __shared__ float q01_s[4 * 8 * QROW];    // 1536 B each
    __shared__ float q02_s[4 * 8 * QROW];
    __shared__ float q12_s[4 * 8 * QROW];
    __shared__ float wmin[4];

    // ---- Phase 1: MFMA matches (binary: wave w = positions w*16..w*16+15) ----
    {
        const float* Abase = bfe + (size_t)b * 4096 + (size_t)(w * 16 + row16) * 64 + kb;
        const bf16x8 a0 = load_bf16x8(Abase);
        const bf16x8 a1 = load_bf16x8(Abase + 32);
        #pragma unroll
        for (int nt = 0; nt < 3; ++nt) {
            const int rule   = nt * 16 + row16;
            const int rule_c = rule < 36 ? rule : 35;    // clamp: dup load, col unused
            const float* Bb  = rb + rule_c * 64 + kb;
            const bf16x8 b0  = load_bf16x8(Bb);
            const bf16x8 b1  = load_bf16x8(Bb + 32);
            f32x4 acc = {0.f, 0.f, 0.f, 0.f};
            acc = __builtin_amdgcn_mfma_f32_16x16x32_bf16(a0, b0, acc, 0, 0, 0);
            acc = __builtin_amdgcn_mfma_f32_16x16x32_bf16(a1, b1, acc, 0, 0, 0);
            // C layout: col = lane&15 (rule), row = (lane>>4)*4 + reg (pos)
            if (rule < 36) {
                const int i = rule / 9;
                const int r = rule - i * 9;
                const int n = r / 3, m = r - n * 3;
                int slot;
                if (n < m)      slot = n + m - 1;              // 01,02,12 -> 0,1,2
                else if (n > m) slot = 3 + n + m;              // 10,20,21 -> 4,5,6
                else            slot = (n == 0) ? 12 : 7 + n;  // 00,11,22 -> 12,8,9
                const int col  = i * 16 + slot;
                const int pos0 = w * 16 + kg * 4;
                #pragma unroll
                for (int t = 0; t < 4; ++t)
                    bm_t[(pos0 + t) * BMT_STRIDE + col] = acc[t];
            }
        }
    }
    // unary match (wave 3): C[obj][i*3+n], K=64; clamp OOB rows (cols/rows unused)
    if (w == 3) {
        const int arow = row16 < 8 ? row16 : 7;
        const float* Ab = uf + (size_t)b * 512 + arow * 64 + kb;
        const bf16x8 a0 = load_bf16x8(Ab);
        const bf16x8 a1 = load_bf16x8(Ab + 32);
        const int brow = row16 < 12 ? row16 : 11;
        const float* Bb = ru + brow * 64 + kb;
        const bf16x8 b0 = load_bf16x8(Bb);
        const bf16x8 b1 = load_bf16x8(Bb + 32);
        f32x4 acc = {0.f, 0.f, 0.f, 0.f};
        acc = __builtin_amdgcn_mfma_f32_16x16x32_bf16(a0, b0, acc, 0, 0, 0);
        acc = __builtin_amdgcn_mfma_f32_16x16x32_bf16(a1, b1, acc, 0, 0, 0);
        if (row16 < 12 && kg < 2) {               // objs 0..7 live in kg 0,1
            const int iu = row16 / 3;
            const int nn = row16 - iu * 3;
            const int uslot = (nn == 0) ? 13 : 9 + nn;   // um0->13, um1->10, um2->11
            #pragma unroll
            for (int t = 0; t < 4; ++t) {
                const int o = kg * 4 + t;
                bm_t[(o * 8 + o) * BMT_STRIDE + iu * 16 + uslot] = acc[t];
            }
        }
    }
    __syncthreads();   // bm_t readable (cross-wave transpose)

    // ---- Phase 2 (wave-local, i = w): pair tables ----
    {
        const int x = lane >> 3;
        const int y = lane & 7;
        const float4 vxy = *(const float4*)&bm_t[(x * 8 + y) * BMT_STRIDE + w * 16 + 0];
        const float4 vyx = *(const float4*)&bm_t[(y * 8 + x) * BMT_STRIDE + w * 16 + 4];
        const float4 vyy = *(const float4*)&bm_t[(y * 8 + y) * BMT_STRIDE + w * 16 + 8];
        const float2 vxx = *(const float2*)&bm_t[(x * 8 + x) * BMT_STRIDE + w * 16 + 12];
        // vxy=[r1,r2,r5,-]  vyx=[r3,r6,r7,-]  vyy=[r4,r8,um1,um2]  vxx=[r0,um0]
        const float q01 = vxx.y + vyy.z + vxx.x + vyy.x + vxy.x + vyx.x;
        const float q02 = vyy.w + vyy.y + vxy.y + vyx.y;
        const float q12 = vxy.z + vyx.z;
        const int ro = (w * 8 + x) * QROW + y;
        q01_s[ro] = q01; q02_s[ro] = q02; q12_s[ro] = q12;
    }
    // no barrier: phase 3 reads only this wave's q rows (in-wave lgkmcnt order)

    // ---- Phase 3 (wave-local): lane = ordered pair pr < 56, sweep cc ----
    float mn = INFINITY;
    if (lane < 56) {
        const int pr = lane;
        const int a  = pr / 7;
        const int o  = pr - a * 7;
        const int bb = o + (o >= a);
        const float base = q01_s[(w * 8 + a) * QROW + bb];
        const float4 r2a = *(const float4*)&q02_s[(w * 8 + a) * QROW];
        const float4 r2b = *(const float4*)&q02_s[(w * 8 + a) * QROW + 4];
        const float4 r1a = *(const float4*)&q12_s[(w * 8 + bb) * QROW];
        const float4 r1b = *(const float4*)&q12_s[(w * 8 + bb) * QROW + 4];
        float v[8];
        v[0] = r2a.x + r1a.x; v[1] = r2a.y + r1a.y;
        v[2] = r2a.z + r1a.z; v[3] = r2a.w + r1a.w;
        v[4] = r2b.x + r1b.x; v[5] = r2b.y + r1b.y;
        v[6] = r2b.z + r1b.z; v[7] = r2b.w + r1b.w;
        #pragma unroll
        for (int cc = 0; cc < 8; ++cc) {
            const float s = (cc == a || cc == bb) ? INFINITY : (base + v[cc]);
            mn = fminf(mn, s);
        }
    }

    // full-wave min reduce (lanes >=56 hold +inf)
    mn = fminf(mn, __shfl_xor(mn, 1));
    mn = fminf(mn, __shfl_xor(mn, 2));
    mn = fminf(mn, __shfl_xor(mn, 4));
    mn = fminf(mn, __shfl_xor(mn, 8));
    mn = fminf(mn, __shfl_xor(mn, 16));
    mn = fminf(mn, __shfl_xor(mn, 32));
    if (lane == 0) wmin[w] = mn;
    __syncthreads();

    if (tid == 0) {
        const float m0 = wmin[0], m1 = wmin[1], m2 = wmin[2], m3 = wmin[3];
        const float mx = fmaxf(fmaxf(m0, m1), fmaxf(m2, m3));
        const float e0 = expf(m0 - mx), e1 = expf(m1 - mx);
        const float e2 = expf(m2 - mx), e3 = expf(m3 - mx);
        const float inv = 1.f / (e0 + e1 + e2 + e3);
        *(float4*)(out + (size_t)b * 4) =
            make_float4((e0 + e1) * inv, (e2 + e3) * inv, 0.f, 0.f);
    }
}

extern "C" void kernel_launch(void* const* d_in, const int* in_sizes, int n_in,
                              void* d_out, int out_size, void* d_ws, size_t ws_size,
                              hipStream_t stream) {
    const float* uf = (const float*)d_in[0];   // (4096,8,64)
    const float* bf = (const float*)d_in[1];   // (4096,8,8,64)
    const float* ru = (const float*)d_in[2];   // (4,3,64)
    const float* rb = (const float*)d_in[3];   // (4,3,3,64)
    float* out = (float*)d_out;                // (4096,4)

    const int B = in_sizes[0] / (8 * 64);      // 4096
    rule_learner_kernel<<<B, 256, 0, stream>>>(uf, bf, ru, rb, out);
}

// Round 7
// 28.917 us; speedup vs baseline: 1.2537x; 1.2537x over previous
//
#include <hip/hip_runtime.h>
#include <math.h>

// B=4096, O=8, E=64, I=4, V=3, P=perm(8,3)=336
// unary_feats  (B,8,64)   f32
// binary_feats (B,8,8,64) f32
// rule_unary   (4,3,64)   f32  = [12][64]
// rule_binary  (4,3,3,64) f32  = [36][64]
// out          (B,4)      f32  (col0=sel0+sel1, col1=sel2+sel3, col2=col3=0)
//
// v7 = v5 (packed-rule prep kernel) + v6 wave-local phases (2 barriers/round)
//      + 2 batch elements per block with full A-prefetch (round-1 HBM latency
//      hidden under round-0 compute), rules loaded once per block.
// bm stored transposed [pos][col], column-permuted slots + unary fused:
//   slots 0..2 : r1(01) r2(02) r5(12)     read at row x*8+y
//   slots 4..6 : r3(10) r6(20) r7(21)     read at row y*8+x
//   slots 8..11: r4(11) r8(22) um1 um2    read at row y*8+y (diag)
//   slots 12,13: r0(00) um0               read at row x*8+x (diag)

typedef __attribute__((ext_vector_type(8))) __bf16 bf16x8;
typedef __attribute__((ext_vector_type(4))) float  f32x4;

#define BMT_STRIDE 68
#define QROW 12

__device__ inline bf16x8 cvt2(const float4 v0, const float4 v1) {
    bf16x8 r;
    r[0] = (__bf16)v0.x; r[1] = (__bf16)v0.y; r[2] = (__bf16)v0.z; r[3] = (__bf16)v0.w;
    r[4] = (__bf16)v1.x; r[5] = (__bf16)v1.y; r[6] = (__bf16)v1.z; r[7] = (__bf16)v1.w;
    return r;
}

// ---- prep: pack rules as bf16 MFMA B-fragments into ws (runs once, 1 block) ----
// bf16 layout: [nt(3)][h(2)][lane(64)][e(8)] then unary [h(2)][lane(64)][e(8)]
__global__ __launch_bounds__(256) void rule_prep_kernel(
    const float* __restrict__ ru, const float* __restrict__ rb,
    __bf16* __restrict__ wsb)
{
    for (int idx = threadIdx.x; idx < 4096; idx += 256) {
        float val;
        if (idx < 3072) {
            const int nt   = idx >> 10;
            const int rem  = idx & 1023;
            const int h    = rem >> 9;
            const int lane = (rem >> 3) & 63;
            const int e    = rem & 7;
            const int rule = nt * 16 + (lane & 15);
            const int k    = h * 32 + (lane >> 4) * 8 + e;
            val = (rule < 36) ? rb[rule * 64 + k] : 0.f;
        } else {
            const int u    = idx - 3072;
            const int h    = u >> 9;
            const int lane = (u >> 3) & 63;
            const int e    = u & 7;
            const int ru16 = lane & 15;
            const int k    = h * 32 + (lane >> 4) * 8 + e;
            val = (ru16 < 12) ? ru[ru16 * 64 + k] : 0.f;
        }
        wsb[idx] = (__bf16)val;
    }
}

__global__ __launch_bounds__(256) void rule_learner_kernel(
    const float* __restrict__ uf,    // (B,8,64)
    const float* __restrict__ bfe,   // (B,8,8,64)
    const bf16x8* __restrict__ wsb,  // packed rule fragments
    float* __restrict__ out)         // (B,4)
{
    const int b0    = blockIdx.x * 2;
    const int tid   = threadIdx.x;
    const int lane  = tid & 63;
    const int w     = tid >> 6;      // wave id = position strip = rule set
    const int row16 = lane & 15;
    const int kg    = lane >> 4;
    const int kb    = kg * 8;

    __shared__ float bm_t[64 * BMT_STRIDE];  // 17408 B
    __shared__ float q01_s[4 * 8 * QROW];    // 1536 B each
    __shared__ float q02_s[4 * 8 * QROW];
    __shared__ float q12_s[4 * 8 * QROW];
    __shared__ float wmin[4];

    // ---- rule fragments: once per block (contiguous lane*16B reads) ----
    bf16x8 rbf[6];
    #pragma unroll
    for (int t = 0; t < 6; ++t) rbf[t] = wsb[t * 64 + lane];
    bf16x8 ruf0, ruf1;
    if (w == 3) { ruf0 = wsb[384 + lane]; ruf1 = wsb[448 + lane]; }

    // ---- A prefetch, BOTH rounds up front (round-1 latency hides under
    //      round-0 compute; plain VGPR loads are not drained by barriers) ----
    float4 ar[2][4];
    {
        const float4* Ab = (const float4*)(bfe + (size_t)b0 * 4096
                                           + (size_t)(w * 16 + row16) * 64 + kb);
        #pragma unroll
        for (int rr = 0; rr < 2; ++rr) {
            ar[rr][0] = Ab[rr * 1024 + 0];
            ar[rr][1] = Ab[rr * 1024 + 1];
            ar[rr][2] = Ab[rr * 1024 + 8];
            ar[rr][3] = Ab[rr * 1024 + 9];
        }
    }
    float4 ur[2][4];
    if (w == 3) {
        const int arow = row16 < 8 ? row16 : 7;
        const float4* Ub = (const float4*)(uf + (size_t)b0 * 512 + arow * 64 + kb);
        #pragma unroll
        for (int rr = 0; rr < 2; ++rr) {
            ur[rr][0] = Ub[rr * 128 + 0];
            ur[rr][1] = Ub[rr * 128 + 1];
            ur[rr][2] = Ub[rr * 128 + 8];
            ur[rr][3] = Ub[rr * 128 + 9];
        }
    }

    #pragma unroll
    for (int rr = 0; rr < 2; ++rr) {
        // ---- Phase 1: MFMA matches ----
        const bf16x8 a0 = cvt2(ar[rr][0], ar[rr][1]);
        const bf16x8 a1 = cvt2(ar[rr][2], ar[rr][3]);
        f32x4 acc[3];
        #pragma unroll
        for (int nt = 0; nt < 3; ++nt) {
            f32x4 z = {0.f, 0.f, 0.f, 0.f};
            z = __builtin_amdgcn_mfma_f32_16x16x32_bf16(a0, rbf[nt * 2 + 0], z, 0, 0, 0);
            z = __builtin_amdgcn_mfma_f32_16x16x32_bf16(a1, rbf[nt * 2 + 1], z, 0, 0, 0);
            acc[nt] = z;
        }
        f32x4 uacc;
        if (w == 3) {
            const bf16x8 ua0 = cvt2(ur[rr][0], ur[rr][1]);
            const bf16x8 ua1 = cvt2(ur[rr][2], ur[rr][3]);
            f32x4 z = {0.f, 0.f, 0.f, 0.f};
            z = __builtin_amdgcn_mfma_f32_16x16x32_bf16(ua0, ruf0, z, 0, 0, 0);
            z = __builtin_amdgcn_mfma_f32_16x16x32_bf16(ua1, ruf1, z, 0, 0, 0);
            uacc = z;
        }
        // stores: C col = lane&15 (rule within tile), row = kg*4 + t (pos)
        #pragma unroll
        for (int nt = 0; nt < 3; ++nt) {
            const int rule = nt * 16 + row16;
            if (rule < 36) {
                const int i = rule / 9;
                const int r = rule - i * 9;
                const int n = r / 3, m = r - n * 3;
                int slot;
                if (n < m)      slot = n + m - 1;              // 01,02,12 -> 0,1,2
                else if (n > m) slot = 3 + n + m;              // 10,20,21 -> 4,5,6
                else            slot = (n == 0) ? 12 : 7 + n;  // 00,11,22 -> 12,8,9
                const int col  = i * 16 + slot;
                const int pos0 = w * 16 + kg * 4;
                #pragma unroll
                for (int t = 0; t < 4; ++t)
                    bm_t[(pos0 + t) * BMT_STRIDE + col] = acc[nt][t];
            }
        }
        if (w == 3 && row16 < 12 && kg < 2) {     // unary: objs 0..7 in kg 0,1
            const int iu = row16 / 3;
            const int nn = row16 - iu * 3;
            const int uslot = (nn == 0) ? 13 : 9 + nn;   // um0->13, um1->10, um2->11
            #pragma unroll
            for (int t = 0; t < 4; ++t) {
                const int o = kg * 4 + t;
                bm_t[(o * 8 + o) * BMT_STRIDE + iu * 16 + uslot] = uacc[t];
            }
        }
        __syncthreads();   // B1: bm_t ready

        // ---- Phase 2 (wave-local, i = w): pair tables ----
        {
            const int x = lane >> 3;
            const int y = lane & 7;
            const float4 vxy = *(const float4*)&bm_t[(x * 8 + y) * BMT_STRIDE + w * 16 + 0];
            const float4 vyx = *(const float4*)&bm_t[(y * 8 + x) * BMT_STRIDE + w * 16 + 4];
            const float4 vyy = *(const float4*)&bm_t[(y * 8 + y) * BMT_STRIDE + w * 16 + 8];
            const float2 vxx = *(const float2*)&bm_t[(x * 8 + x) * BMT_STRIDE + w * 16 + 12];
            // vxy=[r1,r2,r5,-]  vyx=[r3,r6,r7,-]  vyy=[r4,r8,um1,um2]  vxx=[r0,um0]
            const float q01 = vxx.y + vyy.z + vxx.x + vyy.x + vxy.x + vyx.x;
            const float q02 = vyy.w + vyy.y + vxy.y + vyx.y;
            const float q12 = vxy.z + vyx.z;
            const int ro = (w * 8 + x) * QROW + y;
            q01_s[ro] = q01; q02_s[ro] = q02; q12_s[ro] = q12;
        }
        // no barrier: phase 3 reads only this wave's q rows (in-wave lgkmcnt order)

        // ---- Phase 3 (wave-local): lane = ordered pair < 56, sweep cc ----
        float mn = INFINITY;
        if (lane < 56) {
            const int a  = lane / 7;
            const int o  = lane - a * 7;
            const int bb = o + (o >= a);
            const float base = q01_s[(w * 8 + a) * QROW + bb];
            const float4 r2a = *(const float4*)&q02_s[(w * 8 + a) * QROW];
            const float4 r2b = *(const float4*)&q02_s[(w * 8 + a) * QROW + 4];
            const float4 r1a = *(const float4*)&q12_s[(w * 8 + bb) * QROW];
            const float4 r1b = *(const float4*)&q12_s[(w * 8 + bb) * QROW + 4];
            float v[8];
            v[0] = r2a.x + r1a.x; v[1] = r2a.y + r1a.y;
            v[2] = r2a.z + r1a.z; v[3] = r2a.w + r1a.w;
            v[4] = r2b.x + r1b.x; v[5] = r2b.y + r1b.y;
            v[6] = r2b.z + r1b.z; v[7] = r2b.w + r1b.w;
            #pragma unroll
            for (int cc = 0; cc < 8; ++cc) {
                const float s = (cc == a || cc == bb) ? INFINITY : (base + v[cc]);
                mn = fminf(mn, s);
            }
        }
        mn = fminf(mn, __shfl_xor(mn, 1));
        mn = fminf(mn, __shfl_xor(mn, 2));
        mn = fminf(mn, __shfl_xor(mn, 4));
        mn = fminf(mn, __shfl_xor(mn, 8));
        mn = fminf(mn, __shfl_xor(mn, 16));
        mn = fminf(mn, __shfl_xor(mn, 32));
        if (lane == 0) wmin[w] = mn;
        __syncthreads();   // B2: wmin ready; bm_t/q free for next round

        if (tid == 0) {
            const float m0 = wmin[0], m1 = wmin[1], m2 = wmin[2], m3 = wmin[3];
            const float mx = fmaxf(fmaxf(m0, m1), fmaxf(m2, m3));
            const float e0 = expf(m0 - mx), e1 = expf(m1 - mx);
            const float e2 = expf(m2 - mx), e3 = expf(m3 - mx);
            const float inv = 1.f / (e0 + e1 + e2 + e3);
            *(float4*)(out + (size_t)(b0 + rr) * 4) =
                make_float4((e0 + e1) * inv, (e2 + e3) * inv, 0.f, 0.f);
        }
        // tid0's wmin reads are safe: other waves' next-round wmin writes sit
        // behind next-round B1, which can't release until this wave arrives.
    }
}

extern "C" void kernel_launch(void* const* d_in, const int* in_sizes, int n_in,
                              void* d_out, int out_size, void* d_ws, size_t ws_size,
                              hipStream_t stream) {
    const float* uf = (const float*)d_in[0];   // (4096,8,64)
    const float* bf = (const float*)d_in[1];   // (4096,8,8,64)
    const float* ru = (const float*)d_in[2];   // (4,3,64)
    const float* rb = (const float*)d_in[3];   // (4,3,3,64)
    float* out = (float*)d_out;                // (4096,4)

    const int B = in_sizes[0] / (8 * 64);      // 4096

    rule_prep_kernel<<<1, 256, 0, stream>>>(ru, rb, (__bf16*)d_ws);
    rule_learner_kernel<<<B / 2, 256, 0, stream>>>(uf, bf, (const bf16x8*)d_ws, out);
}